// Round 6
// baseline (366.773 us; speedup 1.0000x reference)
//
#include <hip/hip_runtime.h>
#include <math.h>

#define NB 8          // batch
#define NN 1024       // nodes
#define NI 64         // input feat
#define EHC 4         // E*H
#define ND 128        // hidden
#define NO 64         // outputs
#define FIN1 512      // E*H*D
#define BN 8192       // B*N
#define LOG2E 1.4426950408889634f

typedef __attribute__((ext_vector_type(8))) short short8;
typedef __attribute__((ext_vector_type(4))) float f32x4;
typedef __attribute__((ext_vector_type(2))) unsigned uint32x2;

__device__ __forceinline__ unsigned short f2bf(float f) {
    union { float f; unsigned u; } v; v.f = f;
    unsigned r = v.u + 0x7FFF + ((v.u >> 16) & 1);
    return (unsigned short)(r >> 16);
}
__device__ __forceinline__ float bf2f(unsigned short u) {
    union { unsigned u; float f; } v; v.u = (unsigned)u << 16;
    return v.f;
}
__device__ __forceinline__ unsigned short f2h(float f) {
    union { _Float16 h; unsigned short u; } v;
    v.h = (_Float16)f;
    return v.u;
}
__device__ __forceinline__ float h2f(unsigned short u) {
    union { unsigned short u; _Float16 h; } v;
    v.u = u;
    return (float)v.h;
}

// -------- prep: W0,W1 -> bf16 WT[eh][d][k]; Wemb -> WembT[d][k]; Wout -> WoutT[o][d] ----
__global__ void prepTk(const float* __restrict__ W0, const float* __restrict__ W1,
                       const float* __restrict__ Wemb, const float* __restrict__ Wout,
                       unsigned short* __restrict__ W0T, unsigned short* __restrict__ W1T,
                       unsigned short* __restrict__ WembT, unsigned short* __restrict__ WoutT) {
    int idx = blockIdx.x * 256 + threadIdx.x;
    if (idx < EHC * ND * ND) {
        int eh = idx >> 14, d = (idx >> 7) & 127, k = idx & 127;
        W0T[idx] = f2bf(W0[((size_t)(eh * ND + k)) * ND + d]);
    }
    int idx1 = idx - EHC * ND * ND;
    if (idx1 >= 0 && idx1 < EHC * ND * FIN1) {
        int eh = idx1 >> 16;
        int r = idx1 & 65535;
        int d = r >> 9, k = r & 511;
        W1T[idx1] = f2bf(W1[((size_t)(eh * FIN1 + k)) * ND + d]);
    }
    int idx2 = idx - (EHC * ND * ND + EHC * ND * FIN1);
    if (idx2 >= 0 && idx2 < ND * NI) {
        int d = idx2 >> 6, k = idx2 & 63;
        WembT[idx2] = f2bf(Wemb[k * ND + d]);
    }
    int idx3 = idx - (EHC * ND * ND + EHC * ND * FIN1 + ND * NI);
    if (idx3 >= 0 && idx3 < ND * NO) {
        int o = idx3 >> 7, d = idx3 & 127;
        WoutT[idx3] = f2bf(Wout[d * NO + o]);
    }
}

// ---------------- fused embed + layer-0 filter GEMM + s1/s2 epilogue ----------------
// s1/s2 written PRE-SCALED by log2(e): leaky_relu is positively homogeneous, so the
// attention kernels can use native exp2 with no extra multiply.
__global__ __launch_bounds__(256, 4) void embwh0k(
    const float* __restrict__ nodes, const unsigned short* __restrict__ WembT,
    const float* __restrict__ bemb, const unsigned short* __restrict__ W0T,
    unsigned short* __restrict__ WhT, const float* __restrict__ a1w,
    const float* __restrict__ a1b, const float* __restrict__ a2w,
    const float* __restrict__ a2b, float* __restrict__ s1, float* __restrict__ s2) {
    int id = blockIdx.x;
    int g = id & 7, s_ = id >> 3;
    int eh = s_ & 3;
    int row0 = ((s_ >> 2) * 8 + g) * 32;   // 4 eh-blocks share row tile, same XCD slot
    int t = threadIdx.x;
    int w = t >> 6, lane = t & 63;
    int m = lane & 15, quad = lane >> 4;

    __shared__ unsigned short stateL[32 * 136];  // 32 rows x 128 d, pad to 136

    // ---- embed via MFMA: state = relu(nodes @ Wemb + bemb) ----
    f32x4 accE[2][2];
#pragma unroll
    for (int mt = 0; mt < 2; ++mt)
#pragma unroll
        for (int nt = 0; nt < 2; ++nt) accE[mt][nt] = (f32x4){0.f, 0.f, 0.f, 0.f};
#pragma unroll
    for (int kt = 0; kt < 2; ++kt) {
        short8 aE[2], bE[2];
#pragma unroll
        for (int mt = 0; mt < 2; ++mt) {
            const float* np = nodes + (size_t)(row0 + mt * 16 + m) * NI + kt * 32 + quad * 8;
            f32x4 v0 = *(const f32x4*)np;
            f32x4 v1 = *(const f32x4*)(np + 4);
            union { unsigned short us[8]; short8 s8; } pk;
#pragma unroll
            for (int r = 0; r < 4; ++r) {
                pk.us[r] = f2bf(v0[r]);
                pk.us[r + 4] = f2bf(v1[r]);
            }
            aE[mt] = pk.s8;
        }
#pragma unroll
        for (int nt = 0; nt < 2; ++nt)
            bE[nt] = *(const short8*)(WembT + (w * 32 + nt * 16 + m) * NI + kt * 32 + quad * 8);
#pragma unroll
        for (int mt = 0; mt < 2; ++mt)
#pragma unroll
            for (int nt = 0; nt < 2; ++nt)
                accE[mt][nt] =
                    __builtin_amdgcn_mfma_f32_16x16x32_bf16(aE[mt], bE[nt], accE[mt][nt], 0, 0, 0);
    }
#pragma unroll
    for (int mt = 0; mt < 2; ++mt)
#pragma unroll
        for (int nt = 0; nt < 2; ++nt) {
            int d = w * 32 + nt * 16 + m;
            float bb = bemb[d];
#pragma unroll
            for (int r = 0; r < 4; ++r) {
                float v = fmaxf(accE[mt][nt][r] + bb, 0.f);
                stateL[(mt * 16 + quad * 4 + r) * 136 + d] = f2bf(v);
            }
        }
    __syncthreads();

    // ---- main GEMM: Wh = state @ W0[eh], K=128, A from LDS ----
    f32x4 acc[2][2];
#pragma unroll
    for (int mt = 0; mt < 2; ++mt)
#pragma unroll
        for (int nt = 0; nt < 2; ++nt) acc[mt][nt] = (f32x4){0.f, 0.f, 0.f, 0.f};
#pragma unroll
    for (int k0 = 0; k0 < ND; k0 += 32) {
        short8 a[2], b[2];
#pragma unroll
        for (int mt = 0; mt < 2; ++mt)
            a[mt] = *(const short8*)&stateL[(mt * 16 + m) * 136 + k0 + quad * 8];
#pragma unroll
        for (int nt = 0; nt < 2; ++nt)
            b[nt] = *(const short8*)(W0T + ((size_t)(eh * ND + w * 32 + nt * 16 + m)) * ND +
                                     k0 + quad * 8);
#pragma unroll
        for (int mt = 0; mt < 2; ++mt)
#pragma unroll
            for (int nt = 0; nt < 2; ++nt)
                acc[mt][nt] =
                    __builtin_amdgcn_mfma_f32_16x16x32_bf16(a[mt], b[nt], acc[mt][nt], 0, 0, 0);
    }

    // ---- epilogue: store WhT + fused s1/s2 ----
    int b_ = row0 >> 10, i0b = row0 & 1023;
    int ehb = eh * NB + b_;
#pragma unroll
    for (int mt = 0; mt < 2; ++mt)
#pragma unroll
        for (int nt = 0; nt < 2; ++nt) {
            int d = w * 32 + nt * 16 + m;
            int i = i0b + mt * 16 + quad * 4;
            union { unsigned short us[4]; unsigned long long u64; } pk;
#pragma unroll
            for (int r = 0; r < 4; ++r) pk.us[r] = f2bf(acc[mt][nt][r]);
            *(unsigned long long*)(WhT + (((size_t)ehb) * ND + d) * NN + i) = pk.u64;
        }
    float w1a = a1w[eh * ND + w * 32 + m], w1b = a1w[eh * ND + w * 32 + 16 + m];
    float w2a = a2w[eh * ND + w * 32 + m], w2b = a2w[eh * ND + w * 32 + 16 + m];
    float p1[2][4], p2[2][4];
#pragma unroll
    for (int mt = 0; mt < 2; ++mt)
#pragma unroll
        for (int r = 0; r < 4; ++r) {
            p1[mt][r] = acc[mt][0][r] * w1a + acc[mt][1][r] * w1b;
            p2[mt][r] = acc[mt][0][r] * w2a + acc[mt][1][r] * w2b;
        }
#pragma unroll
    for (int off = 8; off >= 1; off >>= 1)
#pragma unroll
        for (int mt = 0; mt < 2; ++mt)
#pragma unroll
            for (int r = 0; r < 4; ++r) {
                p1[mt][r] += __shfl_xor(p1[mt][r], off);
                p2[mt][r] += __shfl_xor(p2[mt][r], off);
            }
    __shared__ float sred[2][4][4][8];
    if (m == 0) {
#pragma unroll
        for (int mt = 0; mt < 2; ++mt)
#pragma unroll
            for (int r = 0; r < 4; ++r) {
                sred[0][w][quad][mt * 4 + r] = p1[mt][r];
                sred[1][w][quad][mt * 4 + r] = p2[mt][r];
            }
    }
    __syncthreads();
    if (t < 32) {
        int mt = t >> 4, quad2 = (t >> 2) & 3, r = t & 3;
        int c = mt * 4 + r;
        float v = sred[0][0][quad2][c] + sred[0][1][quad2][c] + sred[0][2][quad2][c] +
                  sred[0][3][quad2][c];
        s1[(size_t)ehb * NN + i0b + t] = (v + a1b[eh]) * LOG2E;
    } else if (t < 64) {
        int tl = t - 32;
        int mt = tl >> 4, quad2 = (tl >> 2) & 3, r = tl & 3;
        int c = mt * 4 + r;
        float v = sred[1][0][quad2][c] + sred[1][1][quad2][c] + sred[1][2][quad2][c] +
                  sred[1][3][quad2][c];
        s2[(size_t)ehb * NN + i0b + tl] = (v + a2b[eh]) * LOG2E;
    }
}

// ---------------- layer-1 filter GEMM (K=512) + s1/s2 epilogue ----------
// Also zeroes `out` (2 MB) for msg1's atomicAdd head (stream-ordered before msg1).
__global__ __launch_bounds__(256, 4) void whgemm1k(
    const unsigned short* __restrict__ state, const unsigned short* __restrict__ WT,
    unsigned short* __restrict__ WhT, const float* __restrict__ a1w,
    const float* __restrict__ a1b, const float* __restrict__ a2w,
    const float* __restrict__ a2b, float* __restrict__ s1, float* __restrict__ s2,
    float* __restrict__ outz) {
    int id = blockIdx.x;
    int g = id & 7, s_ = id >> 3;
    int eh = s_ & 3;
    int row0 = ((s_ >> 2) * 8 + g) * 32;
    int t = threadIdx.x;
    int w = t >> 6, lane = t & 63;
    int m = lane & 15, quad = lane >> 4;

    // zero out-slice for the fused head (out consumed only by msg1, later in stream)
    {
        f32x4 z = (f32x4){0.f, 0.f, 0.f, 0.f};
        for (int idx = t; idx < 128; idx += 256) ((f32x4*)outz)[(size_t)id * 128 + idx] = z;
    }

    f32x4 acc[2][2];
#pragma unroll
    for (int mt = 0; mt < 2; ++mt)
#pragma unroll
        for (int nt = 0; nt < 2; ++nt) acc[mt][nt] = (f32x4){0.f, 0.f, 0.f, 0.f};

    const unsigned short* Ab = state + (size_t)(row0 + m) * FIN1 + quad * 8;
    const unsigned short* Bb = WT + ((size_t)eh * ND + w * 32 + m) * FIN1 + quad * 8;
#pragma unroll 4
    for (int k0 = 0; k0 < FIN1; k0 += 32) {
        short8 a[2], b[2];
#pragma unroll
        for (int mt = 0; mt < 2; ++mt)
            a[mt] = *(const short8*)(Ab + (size_t)mt * 16 * FIN1 + k0);
#pragma unroll
        for (int nt = 0; nt < 2; ++nt)
            b[nt] = *(const short8*)(Bb + (size_t)nt * 16 * FIN1 + k0);
#pragma unroll
        for (int mt = 0; mt < 2; ++mt)
#pragma unroll
            for (int nt = 0; nt < 2; ++nt)
                acc[mt][nt] =
                    __builtin_amdgcn_mfma_f32_16x16x32_bf16(a[mt], b[nt], acc[mt][nt], 0, 0, 0);
    }
    int b_ = row0 >> 10, i0b = row0 & 1023;
    int ehb = eh * NB + b_;
#pragma unroll
    for (int mt = 0; mt < 2; ++mt)
#pragma unroll
        for (int nt = 0; nt < 2; ++nt) {
            int d = w * 32 + nt * 16 + m;
            int i = i0b + mt * 16 + quad * 4;
            union { unsigned short us[4]; unsigned long long u64; } pk;
#pragma unroll
            for (int r = 0; r < 4; ++r) pk.us[r] = f2bf(acc[mt][nt][r]);
            *(unsigned long long*)(WhT + (((size_t)ehb) * ND + d) * NN + i) = pk.u64;
        }
    float w1a = a1w[eh * ND + w * 32 + m], w1b = a1w[eh * ND + w * 32 + 16 + m];
    float w2a = a2w[eh * ND + w * 32 + m], w2b = a2w[eh * ND + w * 32 + 16 + m];
    float p1[2][4], p2[2][4];
#pragma unroll
    for (int mt = 0; mt < 2; ++mt)
#pragma unroll
        for (int r = 0; r < 4; ++r) {
            p1[mt][r] = acc[mt][0][r] * w1a + acc[mt][1][r] * w1b;
            p2[mt][r] = acc[mt][0][r] * w2a + acc[mt][1][r] * w2b;
        }
#pragma unroll
    for (int off = 8; off >= 1; off >>= 1)
#pragma unroll
        for (int mt = 0; mt < 2; ++mt)
#pragma unroll
            for (int r = 0; r < 4; ++r) {
                p1[mt][r] += __shfl_xor(p1[mt][r], off);
                p2[mt][r] += __shfl_xor(p2[mt][r], off);
            }
    __shared__ float sred[2][4][4][8];
    if (m == 0) {
#pragma unroll
        for (int mt = 0; mt < 2; ++mt)
#pragma unroll
            for (int r = 0; r < 4; ++r) {
                sred[0][w][quad][mt * 4 + r] = p1[mt][r];
                sred[1][w][quad][mt * 4 + r] = p2[mt][r];
            }
    }
    __syncthreads();
    if (t < 32) {
        int mt = t >> 4, quad2 = (t >> 2) & 3, r = t & 3;
        int c = mt * 4 + r;
        float v = sred[0][0][quad2][c] + sred[0][1][quad2][c] + sred[0][2][quad2][c] +
                  sred[0][3][quad2][c];
        s1[(size_t)ehb * NN + i0b + t] = (v + a1b[eh]) * LOG2E;
    } else if (t < 64) {
        int tl = t - 32;
        int mt = tl >> 4, quad2 = (tl >> 2) & 3, r = tl & 3;
        int c = mt * 4 + r;
        float v = sred[1][0][quad2][c] + sred[1][1][quad2][c] + sred[1][2][quad2][c] +
                  sred[1][3][quad2][c];
        s2[(size_t)ehb * NN + i0b + tl] = (v + a2b[eh]) * LOG2E;
    }
}

// ---------------- column sums (no-max softmax): Spart[ic][eh][b][j] ----
// edgesP: TWO f16 planes [e][b][i][j], values pre-scaled by log2e.
template <int CONV>
__global__ __launch_bounds__(256, 4) void colsumk(const float* __restrict__ edges,
                                                  unsigned short* __restrict__ edgesP,
                                                  const float* __restrict__ s1,
                                                  const float* __restrict__ s2,
                                                  float* __restrict__ Spart) {
    const size_t PO = (size_t)NB * NN * NN;   // plane stride (ushort units)
    int jt = blockIdx.x, b = blockIdx.y, ic = blockIdx.z;
    int t = threadIdx.x;
    int jp = t & 31, is = t >> 5;          // j-pair, i-chunk (16 i each)
    int j = jt * 64 + jp * 2;
    __shared__ float s1L[4][128];
    for (int idx = t; idx < 512; idx += 256) {
        int eh = idx >> 7;
        s1L[eh][idx & 127] = s1[((size_t)eh * NB + b) * NN + ic * 128 + (idx & 127)];
    }
    __syncthreads();
    float s2v[4][2], acc4[4][2];
#pragma unroll
    for (int eh = 0; eh < 4; ++eh) {
        s2v[eh][0] = s2[((size_t)eh * NB + b) * NN + j];
        s2v[eh][1] = s2[((size_t)eh * NB + b) * NN + j + 1];
        acc4[eh][0] = 0.f;
        acc4[eh][1] = 0.f;
    }
    int irow0 = ic * 128 + is * 16;
    const float4* ep = (const float4*)edges + (size_t)(b * NN + irow0) * (NN / 2) + jt * 32 + jp;
    unsigned short* pb = edgesP + (size_t)(b * NN + irow0) * NN + j;
#pragma unroll 4
    for (int ii = 0; ii < 16; ++ii) {
        unsigned q0, q1;
        if (CONV) {
            float4 ev = ep[(size_t)ii * (NN / 2)];
            q0 = (unsigned)f2h(ev.x * LOG2E) | ((unsigned)f2h(ev.z * LOG2E) << 16);
            q1 = (unsigned)f2h(ev.y * LOG2E) | ((unsigned)f2h(ev.w * LOG2E) << 16);
            *(unsigned*)(pb + (size_t)ii * NN) = q0;
            *(unsigned*)(pb + PO + (size_t)ii * NN) = q1;
        } else {
            q0 = *(const unsigned*)(pb + (size_t)ii * NN);
            q1 = *(const unsigned*)(pb + PO + (size_t)ii * NN);
        }
        float p0lo = h2f((unsigned short)(q0 & 0xffff)), p0hi = h2f((unsigned short)(q0 >> 16));
        float p1lo = h2f((unsigned short)(q1 & 0xffff)), p1hi = h2f((unsigned short)(q1 >> 16));
#pragma unroll
        for (int eh = 0; eh < 4; ++eh) {
            float sv = s1L[eh][is * 16 + ii];
            float x0 = sv + s2v[eh][0];
            x0 = fmaxf(x0, 0.2f * x0);
            acc4[eh][0] += __builtin_exp2f(x0 + (eh < 2 ? p0lo : p1lo));
            float x1 = sv + s2v[eh][1];
            x1 = fmaxf(x1, 0.2f * x1);
            acc4[eh][1] += __builtin_exp2f(x1 + (eh < 2 ? p0hi : p1hi));
        }
    }
    __shared__ float red[8][4][64];  // [is][eh][jl]
#pragma unroll
    for (int eh = 0; eh < 4; ++eh) {
        red[is][eh][jp * 2] = acc4[eh][0];
        red[is][eh][jp * 2 + 1] = acc4[eh][1];
    }
    __syncthreads();
    if (t < 256) {
        int eho = t >> 6, jlo = t & 63;
        float Sv = 0.f;
#pragma unroll
        for (int isx = 0; isx < 8; ++isx) Sv += red[isx][eho][jlo];
        Spart[(((size_t)ic * EHC + eho) * NB + b) * NN + jt * 64 + jlo] = Sv;
    }
}

// ---------------- whsck: fold 1/S_j into Wh IN PLACE: WhT[ehb][d][j] *= 1/S[ehb][j] ----
__global__ __launch_bounds__(256) void whsck(const float* __restrict__ Spart,
                                             unsigned short* __restrict__ WhT) {
    int id = blockIdx.x;
    int ehb = id >> 3, dc = id & 7;
    int t = threadIdx.x;
    __shared__ float sinv[NN];
    const size_t pstr = (size_t)EHC * NB * NN;
    int base = ehb * NN;
    for (int jj = t; jj < NN; jj += 256) {
        float S = 0.f;
#pragma unroll
        for (int ic = 0; ic < 8; ++ic) S += Spart[(size_t)ic * pstr + base + jj];
        sinv[jj] = 1.0f / S;
    }
    __syncthreads();
#pragma unroll 2
    for (int dr = 0; dr < 16; ++dr) {
        unsigned short* row = WhT + ((size_t)ehb * ND + dc * 16 + dr) * NN;
        int jj = t * 4;
        union { unsigned short us[4]; unsigned long long u64; } v;
        v.u64 = *(unsigned long long*)(row + jj);
#pragma unroll
        for (int k = 0; k < 4; ++k) v.us[k] = f2bf(bf2f(v.us[k]) * sinv[jj + k]);
        *(unsigned long long*)(row + jj) = v.u64;
    }
}

// ---------------- fused msg v6: reg-P + j-split + prefetch + cvt_pk ----------------
// 1024 blocks x 512 thr (2 blocks/CU resident, 16 waves/CU, 4/SIMD).
// Block = (itile32, eh, b). Wave w -> (ih=w&1, dh=(w>>1)&1, jh=w>>2): i16 x d64 x j512.
// Per kc (16 per wave): 4 A loads + 1 E load (all 13-bit-immediate offsets), 8 reg-P
// (exp2 + v_cvt_pk_bf16_f32), 4 MFMA. A/E double-buffered (software prefetch).
// jh pairs reduce partial C via one LDS buffer + one barrier. WhS pre-scaled by 1/S.
__global__ __launch_bounds__(512, 4) void msgk(const unsigned short* __restrict__ edgesP,
                                               const unsigned short* __restrict__ WhS,
                                               const float* __restrict__ s1,
                                               const float* __restrict__ s2,
                                               const float* __restrict__ sb,
                                               unsigned short* __restrict__ out0,
                                               const unsigned short* __restrict__ WoutT,
                                               const float* __restrict__ bout,
                                               float* __restrict__ out, int mode) {
    int id = blockIdx.x;
    int b = id & 7;                  // XCD slot: same-b blocks share an L2
    int s_ = id >> 3;
    int eh = s_ & 3;
    int itile = s_ >> 2;             // 0..31 (32 i per block)
    int e = eh >> 1;
    int t = threadIdx.x;
    int w = t >> 6, lane = t & 63;
    int n = lane & 15, quad = lane >> 4;
    int ih = w & 1, dh = (w >> 1) & 1, jh = w >> 2;
    int i0b = itile * 32;
    int i0w = i0b + ih * 16;
    int d0w = dh * 64;
    int j0w = jh * 512;

    __shared__ float stL[NN];                 // s2[j] (4 KB)
    __shared__ float accL[2][2][16][68];      // jh-reduce buffer (17.4 KB)
    __shared__ unsigned short eluL[32][136];  // mode1 head staging (8.7 KB)

    int base = (eh * NB + b) * NN;
    for (int jj = t; jj < NN; jj += 512) stL[jj] = s2[base + jj];
    float s1r = s1[base + i0w + n];
    __syncthreads();   // stL ready; no barriers in K-loop

    f32x4 acc[4];
#pragma unroll
    for (int dt = 0; dt < 4; ++dt) acc[dt] = (f32x4){0.f, 0.f, 0.f, 0.f};

    // A: rows d = d0w + dt*16 + n of WhS[ehb]; E: row i = i0w + n of plane e.
    // Both bases fold j0w and quad*8, so loop offsets are compile-time immediates.
    const unsigned short* Ap =
        WhS + (size_t)base * ND + (size_t)(d0w + n) * NN + j0w + quad * 8;
    const unsigned short* Ep =
        edgesP + ((size_t)(e * NB + b) * NN + i0w + n) * NN + j0w + quad * 8;

    short8 aA[4], aB[4], evA, evB;
    auto LA = [&](short8* a, int jo) {
#pragma unroll
        for (int dt = 0; dt < 4; ++dt)
            a[dt] = *(const short8*)(Ap + (size_t)(dt * 16) * NN + jo);
    };
    auto PST = [&](const short8* a, short8 ev, int jo) {
        f32x4 st0 = *(const f32x4*)&stL[j0w + jo + quad * 8];
        f32x4 st1 = *(const f32x4*)&stL[j0w + jo + quad * 8 + 4];
        float p[8];
#pragma unroll
        for (int r = 0; r < 8; ++r) {
            float x = s1r + (r < 4 ? st0[r] : st1[r - 4]);
            x = fmaxf(x, 0.2f * x);
            x += h2f((unsigned short)ev[r]);
            p[r] = __builtin_exp2f(x);
        }
        union { unsigned u[4]; short8 s8; } pk;
#pragma unroll
        for (int r2 = 0; r2 < 4; ++r2)
            asm("v_cvt_pk_bf16_f32 %0, %1, %2"
                : "=v"(pk.u[r2])
                : "v"(p[2 * r2]), "v"(p[2 * r2 + 1]));
#pragma unroll
        for (int dt = 0; dt < 4; ++dt)
            acc[dt] = __builtin_amdgcn_mfma_f32_16x16x32_bf16(a[dt], pk.s8, acc[dt], 0, 0, 0);
    };

    LA(aA, 0);
    evA = *(const short8*)(Ep + 0);
#pragma unroll
    for (int kc2 = 0; kc2 < 8; ++kc2) {
        int jo = kc2 * 64;
        LA(aB, jo + 32);
        evB = *(const short8*)(Ep + jo + 32);
        PST(aA, evA, jo);
        if (kc2 < 7) {
            LA(aA, jo + 64);
            evA = *(const short8*)(Ep + jo + 64);
        }
        PST(aB, evB, jo + 32);
    }

    // ---- jh-pair reduce: one barrier ----
    if (jh == 1) {
#pragma unroll
        for (int dt = 0; dt < 4; ++dt)
            *(f32x4*)&accL[ih][dh][n][dt * 16 + quad * 4] = acc[dt];
    }
    __syncthreads();
    if (jh == 0) {
#pragma unroll
        for (int dt = 0; dt < 4; ++dt) {
            f32x4 o2 = *(const f32x4*)&accL[ih][dh][n][dt * 16 + quad * 4];
#pragma unroll
            for (int r = 0; r < 4; ++r) acc[dt][r] += o2[r];
        }
    }

    // ---- epilogue ----
    if (mode == 0) {
        if (jh == 0) {
            int i = i0w + n;
#pragma unroll
            for (int dt = 0; dt < 4; ++dt) {
                int d0g = d0w + dt * 16 + quad * 4;
                f32x4 sbv = *(const f32x4*)&sb[eh * ND + d0g];
                union { unsigned short us[4]; unsigned long long u64; } pk;
#pragma unroll
                for (int r = 0; r < 4; ++r) pk.us[r] = f2bf(acc[dt][r] + sbv[r]);
                *(unsigned long long*)(out0 + (size_t)(b * NN + i) * FIN1 + eh * ND + d0g) =
                    pk.u64;
            }
        }
    } else {
        // fused head: out[i][o] += 0.25*(elu(C+sb) @ Wout + bout)
        if (jh == 0) {
#pragma unroll
            for (int dt = 0; dt < 4; ++dt) {
                int d0g = d0w + dt * 16 + quad * 4;
                f32x4 sbv = *(const f32x4*)&sb[eh * ND + d0g];
                union { unsigned short us[4]; unsigned long long u64; } pk;
#pragma unroll
                for (int r = 0; r < 4; ++r) {
                    float v = acc[dt][r] + sbv[r];
                    pk.us[r] = f2bf(v > 0.f ? v : expm1f(v));
                }
                *(unsigned long long*)&eluL[ih * 16 + n][d0g] = pk.u64;
            }
        }
        __syncthreads();
        // head mini-GEMM: 8 waves = (ihh = w&1) x (ot = w>>2? no: w>>1 0..3): i16 x o16
        int ihh = w & 1, ot = w >> 1;   // ot 0..3
        int o = ot * 16 + n;
        f32x4 hacc = (f32x4){0.f, 0.f, 0.f, 0.f};
#pragma unroll
        for (int k0 = 0; k0 < 4; ++k0) {
            short8 av = *(const short8*)&eluL[ihh * 16 + n][k0 * 32 + quad * 8];
            short8 bv = *(const short8*)(WoutT + (size_t)o * ND + k0 * 32 + quad * 8);
            hacc = __builtin_amdgcn_mfma_f32_16x16x32_bf16(av, bv, hacc, 0, 0, 0);
        }
        float bo = bout[o];
        float* op = out + (size_t)(b * NN + i0b + ihh * 16 + quad * 4) * NO + o;
#pragma unroll
        for (int r = 0; r < 4; ++r)
            atomicAdd(op + (size_t)r * NO, 0.25f * hacc[r] + 0.25f * bo);
    }
}

extern "C" void kernel_launch(void* const* d_in, const int* in_sizes, int n_in,
                              void* d_out, int out_size, void* d_ws, size_t ws_size,
                              hipStream_t stream) {
    const float* nodes = (const float*)d_in[0];
    const float* edges = (const float*)d_in[1];
    const float* Wemb = (const float*)d_in[2];
    const float* bemb = (const float*)d_in[3];
    const float* W0 = (const float*)d_in[4];
    const float* A1w0 = (const float*)d_in[5];
    const float* A1b0 = (const float*)d_in[6];
    const float* A2w0 = (const float*)d_in[7];
    const float* A2b0 = (const float*)d_in[8];
    const float* SB0 = (const float*)d_in[9];
    const float* W1 = (const float*)d_in[10];
    const float* A1w1 = (const float*)d_in[11];
    const float* A1b1 = (const float*)d_in[12];
    const float* A2w1 = (const float*)d_in[13];
    const float* A2b1 = (const float*)d_in[14];
    const float* SB1 = (const float*)d_in[15];
    const float* Wout = (const float*)d_in[16];
    const float* bout = (const float*)d_in[17];
    float* out = (float*)d_out;

    char* p = (char*)d_ws;
    auto alloc = [&](size_t bytes) {
        char* r = p;
        p += (bytes + 255) & ~(size_t)255;
        return r;
    };
    unsigned short* W0T = (unsigned short*)alloc((size_t)EHC * ND * ND * 2);
    unsigned short* W1T = (unsigned short*)alloc((size_t)EHC * ND * FIN1 * 2);
    unsigned short* WembT = (unsigned short*)alloc((size_t)ND * NI * 2);
    unsigned short* WoutT = (unsigned short*)alloc((size_t)ND * NO * 2);
    unsigned short* WhT = (unsigned short*)alloc((size_t)EHC * BN * ND * 2);
    unsigned short* state1 = (unsigned short*)alloc((size_t)BN * FIN1 * 2);
    float* s1b = (float*)alloc((size_t)EHC * BN * 4);
    float* s2b = (float*)alloc((size_t)EHC * BN * 4);
    float* Spart = (float*)alloc((size_t)8 * EHC * BN * 4);
    unsigned short* edgesP = (unsigned short*)alloc((size_t)2 * NB * NN * NN * 2);

    prepTk<<<1344, 256, 0, stream>>>(W0, W1, Wemb, Wout, W0T, W1T, WembT, WoutT);
    // layer 0 (embed fused into filter GEMM)
    embwh0k<<<1024, 256, 0, stream>>>(nodes, WembT, bemb, W0T, WhT, A1w0, A1b0, A2w0, A2b0,
                                      s1b, s2b);
    colsumk<1><<<dim3(NN / 64, NB, 8), 256, 0, stream>>>(edges, edgesP, s1b, s2b, Spart);
    whsck<<<256, 256, 0, stream>>>(Spart, WhT);
    msgk<<<1024, 512, 0, stream>>>(edgesP, WhT, s1b, s2b, SB0, state1, WoutT, bout, out, 0);
    // layer 1 (whgemm1k also zeroes `out` for the fused head)
    whgemm1k<<<1024, 256, 0, stream>>>(state1, W1T, WhT, A1w1, A1b1, A2w1, A2b1, s1b, s2b,
                                       out);
    colsumk<0><<<dim3(NN / 64, NB, 8), 256, 0, stream>>>(edges, edgesP, s1b, s2b, Spart);
    whsck<<<256, 256, 0, stream>>>(Spart, WhT);
    msgk<<<1024, 512, 0, stream>>>(edgesP, WhT, s1b, s2b, SB1, state1, WoutT, bout, out, 1);
}

// Round 7
// 268.735 us; speedup vs baseline: 1.3648x; 1.3648x over previous
//
#include <hip/hip_runtime.h>
#include <math.h>

#define NB 8          // batch
#define NN 1024       // nodes
#define NI 64         // input feat
#define EHC 4         // E*H
#define ND 128        // hidden
#define NO 64         // outputs
#define FIN1 512      // E*H*D
#define BN 8192       // B*N
#define LOG2E 1.4426950408889634f

typedef __attribute__((ext_vector_type(8))) short short8;
typedef __attribute__((ext_vector_type(4))) float f32x4;

__device__ __forceinline__ unsigned short f2bf(float f) {
    union { float f; unsigned u; } v; v.f = f;
    unsigned r = v.u + 0x7FFF + ((v.u >> 16) & 1);
    return (unsigned short)(r >> 16);
}
__device__ __forceinline__ float bf2f(unsigned short u) {
    union { unsigned u; float f; } v; v.u = (unsigned)u << 16;
    return v.f;
}
__device__ __forceinline__ unsigned short f2h(float f) {
    union { _Float16 h; unsigned short u; } v;
    v.h = (_Float16)f;
    return v.u;
}
__device__ __forceinline__ float h2f(unsigned short u) {
    union { unsigned short u; _Float16 h; } v;
    v.u = u;
    return (float)v.h;
}

// -------- prep: W0,W1 -> bf16 WT[eh][d][k]; Wemb -> WembT[d][k]; Wout -> WoutT[o][d] ----
__global__ void prepTk(const float* __restrict__ W0, const float* __restrict__ W1,
                       const float* __restrict__ Wemb, const float* __restrict__ Wout,
                       unsigned short* __restrict__ W0T, unsigned short* __restrict__ W1T,
                       unsigned short* __restrict__ WembT, unsigned short* __restrict__ WoutT) {
    int idx = blockIdx.x * 256 + threadIdx.x;
    if (idx < EHC * ND * ND) {
        int eh = idx >> 14, d = (idx >> 7) & 127, k = idx & 127;
        W0T[idx] = f2bf(W0[((size_t)(eh * ND + k)) * ND + d]);
    }
    int idx1 = idx - EHC * ND * ND;
    if (idx1 >= 0 && idx1 < EHC * ND * FIN1) {
        int eh = idx1 >> 16;
        int r = idx1 & 65535;
        int d = r >> 9, k = r & 511;
        W1T[idx1] = f2bf(W1[((size_t)(eh * FIN1 + k)) * ND + d]);
    }
    int idx2 = idx - (EHC * ND * ND + EHC * ND * FIN1);
    if (idx2 >= 0 && idx2 < ND * NI) {
        int d = idx2 >> 6, k = idx2 & 63;
        WembT[idx2] = f2bf(Wemb[k * ND + d]);
    }
    int idx3 = idx - (EHC * ND * ND + EHC * ND * FIN1 + ND * NI);
    if (idx3 >= 0 && idx3 < ND * NO) {
        int o = idx3 >> 7, d = idx3 & 127;
        WoutT[idx3] = f2bf(Wout[d * NO + o]);
    }
}

// ---------------- fused embed + layer-0 filter GEMM + s1/s2 epilogue ----------------
// s1/s2 written PRE-SCALED by log2(e): leaky_relu is positively homogeneous, so the
// attention kernels can use native exp2 with no extra multiply.
__global__ __launch_bounds__(256, 4) void embwh0k(
    const float* __restrict__ nodes, const unsigned short* __restrict__ WembT,
    const float* __restrict__ bemb, const unsigned short* __restrict__ W0T,
    unsigned short* __restrict__ WhT, const float* __restrict__ a1w,
    const float* __restrict__ a1b, const float* __restrict__ a2w,
    const float* __restrict__ a2b, float* __restrict__ s1, float* __restrict__ s2) {
    int id = blockIdx.x;
    int g = id & 7, s_ = id >> 3;
    int eh = s_ & 3;
    int row0 = ((s_ >> 2) * 8 + g) * 32;   // 4 eh-blocks share row tile, same XCD slot
    int t = threadIdx.x;
    int w = t >> 6, lane = t & 63;
    int m = lane & 15, quad = lane >> 4;

    __shared__ unsigned short stateL[32 * 136];  // 32 rows x 128 d, pad to 136

    // ---- embed via MFMA: state = relu(nodes @ Wemb + bemb) ----
    f32x4 accE[2][2];
#pragma unroll
    for (int mt = 0; mt < 2; ++mt)
#pragma unroll
        for (int nt = 0; nt < 2; ++nt) accE[mt][nt] = (f32x4){0.f, 0.f, 0.f, 0.f};
#pragma unroll
    for (int kt = 0; kt < 2; ++kt) {
        short8 aE[2], bE[2];
#pragma unroll
        for (int mt = 0; mt < 2; ++mt) {
            const float* np = nodes + (size_t)(row0 + mt * 16 + m) * NI + kt * 32 + quad * 8;
            f32x4 v0 = *(const f32x4*)np;
            f32x4 v1 = *(const f32x4*)(np + 4);
            union { unsigned short us[8]; short8 s8; } pk;
#pragma unroll
            for (int r = 0; r < 4; ++r) {
                pk.us[r] = f2bf(v0[r]);
                pk.us[r + 4] = f2bf(v1[r]);
            }
            aE[mt] = pk.s8;
        }
#pragma unroll
        for (int nt = 0; nt < 2; ++nt)
            bE[nt] = *(const short8*)(WembT + (w * 32 + nt * 16 + m) * NI + kt * 32 + quad * 8);
#pragma unroll
        for (int mt = 0; mt < 2; ++mt)
#pragma unroll
            for (int nt = 0; nt < 2; ++nt)
                accE[mt][nt] =
                    __builtin_amdgcn_mfma_f32_16x16x32_bf16(aE[mt], bE[nt], accE[mt][nt], 0, 0, 0);
    }
#pragma unroll
    for (int mt = 0; mt < 2; ++mt)
#pragma unroll
        for (int nt = 0; nt < 2; ++nt) {
            int d = w * 32 + nt * 16 + m;
            float bb = bemb[d];
#pragma unroll
            for (int r = 0; r < 4; ++r) {
                float v = fmaxf(accE[mt][nt][r] + bb, 0.f);
                stateL[(mt * 16 + quad * 4 + r) * 136 + d] = f2bf(v);
            }
        }
    __syncthreads();

    // ---- main GEMM: Wh = state @ W0[eh], K=128, A from LDS ----
    f32x4 acc[2][2];
#pragma unroll
    for (int mt = 0; mt < 2; ++mt)
#pragma unroll
        for (int nt = 0; nt < 2; ++nt) acc[mt][nt] = (f32x4){0.f, 0.f, 0.f, 0.f};
#pragma unroll
    for (int k0 = 0; k0 < ND; k0 += 32) {
        short8 a[2], b[2];
#pragma unroll
        for (int mt = 0; mt < 2; ++mt)
            a[mt] = *(const short8*)&stateL[(mt * 16 + m) * 136 + k0 + quad * 8];
#pragma unroll
        for (int nt = 0; nt < 2; ++nt)
            b[nt] = *(const short8*)(W0T + ((size_t)(eh * ND + w * 32 + nt * 16 + m)) * ND +
                                     k0 + quad * 8);
#pragma unroll
        for (int mt = 0; mt < 2; ++mt)
#pragma unroll
            for (int nt = 0; nt < 2; ++nt)
                acc[mt][nt] =
                    __builtin_amdgcn_mfma_f32_16x16x32_bf16(a[mt], b[nt], acc[mt][nt], 0, 0, 0);
    }

    // ---- epilogue: store WhT + fused s1/s2 ----
    int b_ = row0 >> 10, i0b = row0 & 1023;
    int ehb = eh * NB + b_;
#pragma unroll
    for (int mt = 0; mt < 2; ++mt)
#pragma unroll
        for (int nt = 0; nt < 2; ++nt) {
            int d = w * 32 + nt * 16 + m;
            int i = i0b + mt * 16 + quad * 4;
            union { unsigned short us[4]; unsigned long long u64; } pk;
#pragma unroll
            for (int r = 0; r < 4; ++r) pk.us[r] = f2bf(acc[mt][nt][r]);
            *(unsigned long long*)(WhT + (((size_t)ehb) * ND + d) * NN + i) = pk.u64;
        }
    float w1a = a1w[eh * ND + w * 32 + m], w1b = a1w[eh * ND + w * 32 + 16 + m];
    float w2a = a2w[eh * ND + w * 32 + m], w2b = a2w[eh * ND + w * 32 + 16 + m];
    float p1[2][4], p2[2][4];
#pragma unroll
    for (int mt = 0; mt < 2; ++mt)
#pragma unroll
        for (int r = 0; r < 4; ++r) {
            p1[mt][r] = acc[mt][0][r] * w1a + acc[mt][1][r] * w1b;
            p2[mt][r] = acc[mt][0][r] * w2a + acc[mt][1][r] * w2b;
        }
#pragma unroll
    for (int off = 8; off >= 1; off >>= 1)
#pragma unroll
        for (int mt = 0; mt < 2; ++mt)
#pragma unroll
            for (int r = 0; r < 4; ++r) {
                p1[mt][r] += __shfl_xor(p1[mt][r], off);
                p2[mt][r] += __shfl_xor(p2[mt][r], off);
            }
    __shared__ float sred[2][4][4][8];
    if (m == 0) {
#pragma unroll
        for (int mt = 0; mt < 2; ++mt)
#pragma unroll
            for (int r = 0; r < 4; ++r) {
                sred[0][w][quad][mt * 4 + r] = p1[mt][r];
                sred[1][w][quad][mt * 4 + r] = p2[mt][r];
            }
    }
    __syncthreads();
    if (t < 32) {
        int mt = t >> 4, quad2 = (t >> 2) & 3, r = t & 3;
        int c = mt * 4 + r;
        float v = sred[0][0][quad2][c] + sred[0][1][quad2][c] + sred[0][2][quad2][c] +
                  sred[0][3][quad2][c];
        s1[(size_t)ehb * NN + i0b + t] = (v + a1b[eh]) * LOG2E;
    } else if (t < 64) {
        int tl = t - 32;
        int mt = tl >> 4, quad2 = (tl >> 2) & 3, r = tl & 3;
        int c = mt * 4 + r;
        float v = sred[1][0][quad2][c] + sred[1][1][quad2][c] + sred[1][2][quad2][c] +
                  sred[1][3][quad2][c];
        s2[(size_t)ehb * NN + i0b + tl] = (v + a2b[eh]) * LOG2E;
    }
}

// ---------------- layer-1 filter GEMM (K=512) + s1/s2 epilogue ----------
// Also zeroes `out` (2 MB) for msg1's atomicAdd head (stream-ordered before msg1).
__global__ __launch_bounds__(256, 4) void whgemm1k(
    const unsigned short* __restrict__ state, const unsigned short* __restrict__ WT,
    unsigned short* __restrict__ WhT, const float* __restrict__ a1w,
    const float* __restrict__ a1b, const float* __restrict__ a2w,
    const float* __restrict__ a2b, float* __restrict__ s1, float* __restrict__ s2,
    float* __restrict__ outz) {
    int id = blockIdx.x;
    int g = id & 7, s_ = id >> 3;
    int eh = s_ & 3;
    int row0 = ((s_ >> 2) * 8 + g) * 32;
    int t = threadIdx.x;
    int w = t >> 6, lane = t & 63;
    int m = lane & 15, quad = lane >> 4;

    // zero out-slice for the fused head (out consumed only by msg1, later in stream)
    {
        f32x4 z = (f32x4){0.f, 0.f, 0.f, 0.f};
        for (int idx = t; idx < 128; idx += 256) ((f32x4*)outz)[(size_t)id * 128 + idx] = z;
    }

    f32x4 acc[2][2];
#pragma unroll
    for (int mt = 0; mt < 2; ++mt)
#pragma unroll
        for (int nt = 0; nt < 2; ++nt) acc[mt][nt] = (f32x4){0.f, 0.f, 0.f, 0.f};

    const unsigned short* Ab = state + (size_t)(row0 + m) * FIN1 + quad * 8;
    const unsigned short* Bb = WT + ((size_t)eh * ND + w * 32 + m) * FIN1 + quad * 8;
#pragma unroll 4
    for (int k0 = 0; k0 < FIN1; k0 += 32) {
        short8 a[2], b[2];
#pragma unroll
        for (int mt = 0; mt < 2; ++mt)
            a[mt] = *(const short8*)(Ab + (size_t)mt * 16 * FIN1 + k0);
#pragma unroll
        for (int nt = 0; nt < 2; ++nt)
            b[nt] = *(const short8*)(Bb + (size_t)nt * 16 * FIN1 + k0);
#pragma unroll
        for (int mt = 0; mt < 2; ++mt)
#pragma unroll
            for (int nt = 0; nt < 2; ++nt)
                acc[mt][nt] =
                    __builtin_amdgcn_mfma_f32_16x16x32_bf16(a[mt], b[nt], acc[mt][nt], 0, 0, 0);
    }
    int b_ = row0 >> 10, i0b = row0 & 1023;
    int ehb = eh * NB + b_;
#pragma unroll
    for (int mt = 0; mt < 2; ++mt)
#pragma unroll
        for (int nt = 0; nt < 2; ++nt) {
            int d = w * 32 + nt * 16 + m;
            int i = i0b + mt * 16 + quad * 4;
            union { unsigned short us[4]; unsigned long long u64; } pk;
#pragma unroll
            for (int r = 0; r < 4; ++r) pk.us[r] = f2bf(acc[mt][nt][r]);
            *(unsigned long long*)(WhT + (((size_t)ehb) * ND + d) * NN + i) = pk.u64;
        }
    float w1a = a1w[eh * ND + w * 32 + m], w1b = a1w[eh * ND + w * 32 + 16 + m];
    float w2a = a2w[eh * ND + w * 32 + m], w2b = a2w[eh * ND + w * 32 + 16 + m];
    float p1[2][4], p2[2][4];
#pragma unroll
    for (int mt = 0; mt < 2; ++mt)
#pragma unroll
        for (int r = 0; r < 4; ++r) {
            p1[mt][r] = acc[mt][0][r] * w1a + acc[mt][1][r] * w1b;
            p2[mt][r] = acc[mt][0][r] * w2a + acc[mt][1][r] * w2b;
        }
#pragma unroll
    for (int off = 8; off >= 1; off >>= 1)
#pragma unroll
        for (int mt = 0; mt < 2; ++mt)
#pragma unroll
            for (int r = 0; r < 4; ++r) {
                p1[mt][r] += __shfl_xor(p1[mt][r], off);
                p2[mt][r] += __shfl_xor(p2[mt][r], off);
            }
    __shared__ float sred[2][4][4][8];
    if (m == 0) {
#pragma unroll
        for (int mt = 0; mt < 2; ++mt)
#pragma unroll
            for (int r = 0; r < 4; ++r) {
                sred[0][w][quad][mt * 4 + r] = p1[mt][r];
                sred[1][w][quad][mt * 4 + r] = p2[mt][r];
            }
    }
    __syncthreads();
    if (t < 32) {
        int mt = t >> 4, quad2 = (t >> 2) & 3, r = t & 3;
        int c = mt * 4 + r;
        float v = sred[0][0][quad2][c] + sred[0][1][quad2][c] + sred[0][2][quad2][c] +
                  sred[0][3][quad2][c];
        s1[(size_t)ehb * NN + i0b + t] = (v + a1b[eh]) * LOG2E;
    } else if (t < 64) {
        int tl = t - 32;
        int mt = tl >> 4, quad2 = (tl >> 2) & 3, r = tl & 3;
        int c = mt * 4 + r;
        float v = sred[1][0][quad2][c] + sred[1][1][quad2][c] + sred[1][2][quad2][c] +
                  sred[1][3][quad2][c];
        s2[(size_t)ehb * NN + i0b + tl] = (v + a2b[eh]) * LOG2E;
    }
}

// ---------------- column sums (no-max softmax): Spart[ic][eh][b][j] ----
// edgesP: TWO f16 planes [e][b][i][j], values pre-scaled by log2e.
template <int CONV>
__global__ __launch_bounds__(256, 4) void colsumk(const float* __restrict__ edges,
                                                  unsigned short* __restrict__ edgesP,
                                                  const float* __restrict__ s1,
                                                  const float* __restrict__ s2,
                                                  float* __restrict__ Spart) {
    const size_t PO = (size_t)NB * NN * NN;   // plane stride (ushort units)
    int jt = blockIdx.x, b = blockIdx.y, ic = blockIdx.z;
    int t = threadIdx.x;
    int jp = t & 31, is = t >> 5;          // j-pair, i-chunk (16 i each)
    int j = jt * 64 + jp * 2;
    __shared__ float s1L[4][128];
    for (int idx = t; idx < 512; idx += 256) {
        int eh = idx >> 7;
        s1L[eh][idx & 127] = s1[((size_t)eh * NB + b) * NN + ic * 128 + (idx & 127)];
    }
    __syncthreads();
    float s2v[4][2], acc4[4][2];
#pragma unroll
    for (int eh = 0; eh < 4; ++eh) {
        s2v[eh][0] = s2[((size_t)eh * NB + b) * NN + j];
        s2v[eh][1] = s2[((size_t)eh * NB + b) * NN + j + 1];
        acc4[eh][0] = 0.f;
        acc4[eh][1] = 0.f;
    }
    int irow0 = ic * 128 + is * 16;
    const float4* ep = (const float4*)edges + (size_t)(b * NN + irow0) * (NN / 2) + jt * 32 + jp;
    unsigned short* pb = edgesP + (size_t)(b * NN + irow0) * NN + j;
#pragma unroll 4
    for (int ii = 0; ii < 16; ++ii) {
        unsigned q0, q1;
        if (CONV) {
            float4 ev = ep[(size_t)ii * (NN / 2)];
            q0 = (unsigned)f2h(ev.x * LOG2E) | ((unsigned)f2h(ev.z * LOG2E) << 16);
            q1 = (unsigned)f2h(ev.y * LOG2E) | ((unsigned)f2h(ev.w * LOG2E) << 16);
            *(unsigned*)(pb + (size_t)ii * NN) = q0;
            *(unsigned*)(pb + PO + (size_t)ii * NN) = q1;
        } else {
            q0 = *(const unsigned*)(pb + (size_t)ii * NN);
            q1 = *(const unsigned*)(pb + PO + (size_t)ii * NN);
        }
        float p0lo = h2f((unsigned short)(q0 & 0xffff)), p0hi = h2f((unsigned short)(q0 >> 16));
        float p1lo = h2f((unsigned short)(q1 & 0xffff)), p1hi = h2f((unsigned short)(q1 >> 16));
#pragma unroll
        for (int eh = 0; eh < 4; ++eh) {
            float sv = s1L[eh][is * 16 + ii];
            float x0 = sv + s2v[eh][0];
            x0 = fmaxf(x0, 0.2f * x0);
            acc4[eh][0] += __builtin_exp2f(x0 + (eh < 2 ? p0lo : p1lo));
            float x1 = sv + s2v[eh][1];
            x1 = fmaxf(x1, 0.2f * x1);
            acc4[eh][1] += __builtin_exp2f(x1 + (eh < 2 ? p0hi : p1hi));
        }
    }
    __shared__ float red[8][4][64];  // [is][eh][jl]
#pragma unroll
    for (int eh = 0; eh < 4; ++eh) {
        red[is][eh][jp * 2] = acc4[eh][0];
        red[is][eh][jp * 2 + 1] = acc4[eh][1];
    }
    __syncthreads();
    if (t < 256) {
        int eho = t >> 6, jlo = t & 63;
        float Sv = 0.f;
#pragma unroll
        for (int isx = 0; isx < 8; ++isx) Sv += red[isx][eho][jlo];
        Spart[(((size_t)ic * EHC + eho) * NB + b) * NN + jt * 64 + jlo] = Sv;
    }
}

// ---------------- whsck: fold 1/S_j into Wh IN PLACE: WhT[ehb][d][j] *= 1/S[ehb][j] ----
__global__ __launch_bounds__(256) void whsck(const float* __restrict__ Spart,
                                             unsigned short* __restrict__ WhT) {
    int id = blockIdx.x;
    int ehb = id >> 3, dc = id & 7;
    int t = threadIdx.x;
    __shared__ float sinv[NN];
    const size_t pstr = (size_t)EHC * NB * NN;
    int base = ehb * NN;
    for (int jj = t; jj < NN; jj += 256) {
        float S = 0.f;
#pragma unroll
        for (int ic = 0; ic < 8; ++ic) S += Spart[(size_t)ic * pstr + base + jj];
        sinv[jj] = 1.0f / S;
    }
    __syncthreads();
#pragma unroll 2
    for (int dr = 0; dr < 16; ++dr) {
        unsigned short* row = WhT + ((size_t)ehb * ND + dc * 16 + dr) * NN;
        int jj = t * 4;
        union { unsigned short us[4]; unsigned long long u64; } v;
        v.u64 = *(unsigned long long*)(row + jj);
#pragma unroll
        for (int k = 0; k < 4; ++k) v.us[k] = f2bf(bf2f(v.us[k]) * sinv[jj + k]);
        *(unsigned long long*)(row + jj) = v.u64;
    }
}

// ---------------- fused msg (R2-proven structure): LDS-P, i64 tile, dbuf pstep --------
// 512 blocks x 512 thr (launch_bounds(512,4) -> 2 blocks/CU). Block = (itile16, eh, b).
// 8 waves each own d16 (MFMA A rows) and 8 i-rows of P-compute (coalesced E loads).
// WhS pre-scaled by 1/S (whsck); edgesP f16 pre-scaled by log2e; s1/s2 pre-scaled.
// mode0: write state1.  mode1: fused head (elu -> LDS -> mini-MFMA @ WoutT -> atomicAdd).
__global__ __launch_bounds__(512, 4) void msgk(const unsigned short* __restrict__ edgesP,
                                               const unsigned short* __restrict__ WhS,
                                               const float* __restrict__ s1,
                                               const float* __restrict__ s2,
                                               const float* __restrict__ sb,
                                               unsigned short* __restrict__ out0,
                                               const unsigned short* __restrict__ WoutT,
                                               const float* __restrict__ bout,
                                               float* __restrict__ out, int mode) {
    int id = blockIdx.x;
    int b = id & 7;                 // XCD slot: same-b blocks share an L2
    int s_ = id >> 3;
    int eh = s_ & 3;
    int itile = s_ >> 2;            // 0..15 (64 i per block)
    int e = eh >> 1;
    int i0 = itile * 64;
    int t = threadIdx.x;
    int w = t >> 6, lane = t & 63;
    int n = lane & 15, quad = lane >> 4;
    int jl = t & 63, ib = w;        // P-compute: 8 rows x 1 col per thread

    __shared__ float stL[NN];                   // s2[j] (4 KB)
    __shared__ unsigned short pA[2][64 * 72];   // P double buffer (18.4 KB)
    __shared__ unsigned short eluL[64][136];    // mode1 head staging (17.4 KB)

    int base = (eh * NB + b) * NN;
    for (int jj = t; jj < NN; jj += 512) stL[jj] = s2[base + jj];
    float s1r[8];
    {
        const f32x4* sp = (const f32x4*)(s1 + base + i0 + ib * 8);
        f32x4 v0 = sp[0], v1 = sp[1];
#pragma unroll
        for (int r = 0; r < 4; ++r) { s1r[r] = v0[r]; s1r[r + 4] = v1[r]; }
    }

    f32x4 acc[4];
#pragma unroll
    for (int nt = 0; nt < 4; ++nt) acc[nt] = (f32x4){0.f, 0.f, 0.f, 0.f};

    // A operand: this wave's 16 d-rows (d = w*16 + n); E: rows i0+ib*8..+8, col jl
    const unsigned short* Ab =
        WhS + ((size_t)base * ND + (size_t)(w * 16 + n) * NN) + quad * 8;
    const unsigned short* Ep = edgesP + ((size_t)(e * NB + b) * NN + i0 + ib * 8) * NN + jl;
    __syncthreads();  // stL ready

    unsigned short evA[8], evB[8];
    short8 aA[2], aB[2];

    auto loadE = [&](unsigned short* ev, int j0) {
#pragma unroll
        for (int q = 0; q < 8; ++q) ev[q] = Ep[(size_t)q * NN + j0];
    };
    auto loadA = [&](short8* av, int j0) {
#pragma unroll
        for (int kt = 0; kt < 2; ++kt)
            av[kt] = *(const short8*)(Ab + kt * 32 + j0);
    };
    auto pstep = [&](const unsigned short* ev, const short8* av, int j0, int buf) {
        float stj = stL[j0 + jl];
#pragma unroll
        for (int q = 0; q < 8; ++q) {
            float x = s1r[q] + stj;
            x = fmaxf(x, 0.2f * x);
            x += h2f(ev[q]);
            pA[buf][(ib * 8 + q) * 72 + jl] = f2bf(__builtin_exp2f(x));
        }
        __syncthreads();
#pragma unroll
        for (int kt = 0; kt < 2; ++kt) {
            short8 bv[4];
#pragma unroll
            for (int nt = 0; nt < 4; ++nt)
                bv[nt] = *(const short8*)&pA[buf][(nt * 16 + n) * 72 + kt * 32 + quad * 8];
#pragma unroll
            for (int nt = 0; nt < 4; ++nt)
                acc[nt] =
                    __builtin_amdgcn_mfma_f32_16x16x32_bf16(av[kt], bv[nt], acc[nt], 0, 0, 0);
        }
    };

    loadE(evA, 0);
    loadA(aA, 0);
    for (int sp2 = 0; sp2 < 8; ++sp2) {
        int j0 = sp2 * 128;
        loadE(evB, j0 + 64);
        loadA(aB, j0 + 64);
        pstep(evA, aA, j0, 0);
        if (sp2 < 7) {
            loadE(evA, j0 + 128);
            loadA(aA, j0 + 128);
        }
        pstep(evB, aB, j0 + 64, 1);
    }

    // epilogue: C row(quad*4+r) = d-local, col(lane&15) = i-local
    int d0 = w * 16 + quad * 4;
    f32x4 sbv = *(const f32x4*)&sb[eh * ND + d0];
    if (mode == 0) {
#pragma unroll
        for (int nt = 0; nt < 4; ++nt) {
            int i = i0 + nt * 16 + n;
            union { unsigned short us[4]; unsigned long long u64; } pk;
#pragma unroll
            for (int r = 0; r < 4; ++r) pk.us[r] = f2bf(acc[nt][r] + sbv[r]);
            *(unsigned long long*)(out0 + (size_t)(b * NN + i) * FIN1 + eh * ND + d0) = pk.u64;
        }
    } else {
        // fused head: out[i][o] += 0.25*(elu(C+sb) @ Wout + bout)
#pragma unroll
        for (int nt = 0; nt < 4; ++nt) {
            union { unsigned short us[4]; unsigned long long u64; } pk;
#pragma unroll
            for (int r = 0; r < 4; ++r) {
                float v = acc[nt][r] + sbv[r];
                pk.us[r] = f2bf(v > 0.f ? v : expm1f(v));
            }
            *(unsigned long long*)&eluL[nt * 16 + n][d0] = pk.u64;
        }
        __syncthreads();
        // head mini-GEMM: 8 waves cover (it 0..3) x (ot 0..3), 2 tiles each
        int it = w & 3, ot0 = w >> 2;
#pragma unroll
        for (int oo = 0; oo < 2; ++oo) {
            int ot = ot0 + oo * 2;
            int o = ot * 16 + n;
            f32x4 hacc = (f32x4){0.f, 0.f, 0.f, 0.f};
#pragma unroll
            for (int k0 = 0; k0 < 4; ++k0) {
                short8 av = *(const short8*)&eluL[it * 16 + n][k0 * 32 + quad * 8];
                short8 bv = *(const short8*)(WoutT + (size_t)o * ND + k0 * 32 + quad * 8);
                hacc = __builtin_amdgcn_mfma_f32_16x16x32_bf16(av, bv, hacc, 0, 0, 0);
            }
            float bo = bout[o];
            float* op = out + (size_t)(b * NN + i0 + it * 16 + quad * 4) * NO + o;
#pragma unroll
            for (int r = 0; r < 4; ++r)
                atomicAdd(op + (size_t)r * NO, 0.25f * hacc[r] + 0.25f * bo);
        }
    }
}

extern "C" void kernel_launch(void* const* d_in, const int* in_sizes, int n_in,
                              void* d_out, int out_size, void* d_ws, size_t ws_size,
                              hipStream_t stream) {
    const float* nodes = (const float*)d_in[0];
    const float* edges = (const float*)d_in[1];
    const float* Wemb = (const float*)d_in[2];
    const float* bemb = (const float*)d_in[3];
    const float* W0 = (const float*)d_in[4];
    const float* A1w0 = (const float*)d_in[5];
    const float* A1b0 = (const float*)d_in[6];
    const float* A2w0 = (const float*)d_in[7];
    const float* A2b0 = (const float*)d_in[8];
    const float* SB0 = (const float*)d_in[9];
    const float* W1 = (const float*)d_in[10];
    const float* A1w1 = (const float*)d_in[11];
    const float* A1b1 = (const float*)d_in[12];
    const float* A2w1 = (const float*)d_in[13];
    const float* A2b1 = (const float*)d_in[14];
    const float* SB1 = (const float*)d_in[15];
    const float* Wout = (const float*)d_in[16];
    const float* bout = (const float*)d_in[17];
    float* out = (float*)d_out;

    char* p = (char*)d_ws;
    auto alloc = [&](size_t bytes) {
        char* r = p;
        p += (bytes + 255) & ~(size_t)255;
        return r;
    };
    unsigned short* W0T = (unsigned short*)alloc((size_t)EHC * ND * ND * 2);
    unsigned short* W1T = (unsigned short*)alloc((size_t)EHC * ND * FIN1 * 2);
    unsigned short* WembT = (unsigned short*)alloc((size_t)ND * NI * 2);
    unsigned short* WoutT = (unsigned short*)alloc((size_t)ND * NO * 2);
    unsigned short* WhT = (unsigned short*)alloc((size_t)EHC * BN * ND * 2);
    unsigned short* state1 = (unsigned short*)alloc((size_t)BN * FIN1 * 2);
    float* s1b = (float*)alloc((size_t)EHC * BN * 4);
    float* s2b = (float*)alloc((size_t)EHC * BN * 4);
    float* Spart = (float*)alloc((size_t)8 * EHC * BN * 4);
    unsigned short* edgesP = (unsigned short*)alloc((size_t)2 * NB * NN * NN * 2);

    prepTk<<<1344, 256, 0, stream>>>(W0, W1, Wemb, Wout, W0T, W1T, WembT, WoutT);
    // layer 0 (embed fused into filter GEMM)
    embwh0k<<<1024, 256, 0, stream>>>(nodes, WembT, bemb, W0T, WhT, A1w0, A1b0, A2w0, A2b0,
                                      s1b, s2b);
    colsumk<1><<<dim3(NN / 64, NB, 8), 256, 0, stream>>>(edges, edgesP, s1b, s2b, Spart);
    whsck<<<256, 256, 0, stream>>>(Spart, WhT);
    msgk<<<512, 512, 0, stream>>>(edgesP, WhT, s1b, s2b, SB0, state1, WoutT, bout, out, 0);
    // layer 1 (whgemm1k also zeroes `out` for the fused head)
    whgemm1k<<<1024, 256, 0, stream>>>(state1, W1T, WhT, A1w1, A1b1, A2w1, A2b1, s1b, s2b,
                                       out);
    colsumk<0><<<dim3(NN / 64, NB, 8), 256, 0, stream>>>(edges, edgesP, s1b, s2b, Spart);
    whsck<<<256, 256, 0, stream>>>(Spart, WhT);
    msgk<<<512, 512, 0, stream>>>(edgesP, WhT, s1b, s2b, SB1, state1, WoutT, bout, out, 1);
}

// Round 8
// 257.776 us; speedup vs baseline: 1.4228x; 1.0425x over previous
//
#include <hip/hip_runtime.h>
#include <math.h>

#define NB 8          // batch
#define NN 1024       // nodes
#define NI 64         // input feat
#define EHC 4         // E*H
#define ND 128        // hidden
#define NO 64         // outputs
#define FIN1 512      // E*H*D
#define BN 8192       // B*N
#define LOG2E 1.4426950408889634f

typedef __attribute__((ext_vector_type(8))) short short8;
typedef __attribute__((ext_vector_type(4))) float f32x4;

__device__ __forceinline__ unsigned short f2bf(float f) {
    union { float f; unsigned u; } v; v.f = f;
    unsigned r = v.u + 0x7FFF + ((v.u >> 16) & 1);
    return (unsigned short)(r >> 16);
}
__device__ __forceinline__ unsigned short f2h(float f) {
    union { _Float16 h; unsigned short u; } v;
    v.h = (_Float16)f;
    return v.u;
}
__device__ __forceinline__ float h2f(unsigned short u) {
    union { unsigned short u; _Float16 h; } v;
    v.u = u;
    return (float)v.h;
}

// -------- prep: W0,W1 -> bf16 WT[eh][d][k]; Wemb -> WembT[d][k]; Wout -> WoutT[o][d] ----
__global__ void prepTk(const float* __restrict__ W0, const float* __restrict__ W1,
                       const float* __restrict__ Wemb, const float* __restrict__ Wout,
                       unsigned short* __restrict__ W0T, unsigned short* __restrict__ W1T,
                       unsigned short* __restrict__ WembT, unsigned short* __restrict__ WoutT) {
    int idx = blockIdx.x * 256 + threadIdx.x;
    if (idx < EHC * ND * ND) {
        int eh = idx >> 14, d = (idx >> 7) & 127, k = idx & 127;
        W0T[idx] = f2bf(W0[((size_t)(eh * ND + k)) * ND + d]);
    }
    int idx1 = idx - EHC * ND * ND;
    if (idx1 >= 0 && idx1 < EHC * ND * FIN1) {
        int eh = idx1 >> 16;
        int r = idx1 & 65535;
        int d = r >> 9, k = r & 511;
        W1T[idx1] = f2bf(W1[((size_t)(eh * FIN1 + k)) * ND + d]);
    }
    int idx2 = idx - (EHC * ND * ND + EHC * ND * FIN1);
    if (idx2 >= 0 && idx2 < ND * NI) {
        int d = idx2 >> 6, k = idx2 & 63;
        WembT[idx2] = f2bf(Wemb[k * ND + d]);
    }
    int idx3 = idx - (EHC * ND * ND + EHC * ND * FIN1 + ND * NI);
    if (idx3 >= 0 && idx3 < ND * NO) {
        int o = idx3 >> 7, d = idx3 & 127;
        WoutT[idx3] = f2bf(Wout[d * NO + o]);
    }
}

// ---------------- fused embed + layer-0 filter GEMM + s1/s2 epilogue ----------------
// s1/s2 written PRE-SCALED by log2(e): leaky_relu is positively homogeneous, so the
// attention kernels can use native exp2 with no extra multiply.
__global__ __launch_bounds__(256, 4) void embwh0k(
    const float* __restrict__ nodes, const unsigned short* __restrict__ WembT,
    const float* __restrict__ bemb, const unsigned short* __restrict__ W0T,
    unsigned short* __restrict__ WhT, const float* __restrict__ a1w,
    const float* __restrict__ a1b, const float* __restrict__ a2w,
    const float* __restrict__ a2b, float* __restrict__ s1, float* __restrict__ s2) {
    int id = blockIdx.x;
    int g = id & 7, s_ = id >> 3;
    int eh = s_ & 3;
    int row0 = ((s_ >> 2) * 8 + g) * 32;   // 4 eh-blocks share row tile, same XCD slot
    int t = threadIdx.x;
    int w = t >> 6, lane = t & 63;
    int m = lane & 15, quad = lane >> 4;

    __shared__ unsigned short stateL[32 * 136];  // 32 rows x 128 d, pad to 136

    // ---- embed via MFMA: state = relu(nodes @ Wemb + bemb) ----
    f32x4 accE[2][2];
#pragma unroll
    for (int mt = 0; mt < 2; ++mt)
#pragma unroll
        for (int nt = 0; nt < 2; ++nt) accE[mt][nt] = (f32x4){0.f, 0.f, 0.f, 0.f};
#pragma unroll
    for (int kt = 0; kt < 2; ++kt) {
        short8 aE[2], bE[2];
#pragma unroll
        for (int mt = 0; mt < 2; ++mt) {
            const float* np = nodes + (size_t)(row0 + mt * 16 + m) * NI + kt * 32 + quad * 8;
            f32x4 v0 = *(const f32x4*)np;
            f32x4 v1 = *(const f32x4*)(np + 4);
            union { unsigned short us[8]; short8 s8; } pk;
#pragma unroll
            for (int r = 0; r < 4; ++r) {
                pk.us[r] = f2bf(v0[r]);
                pk.us[r + 4] = f2bf(v1[r]);
            }
            aE[mt] = pk.s8;
        }
#pragma unroll
        for (int nt = 0; nt < 2; ++nt)
            bE[nt] = *(const short8*)(WembT + (w * 32 + nt * 16 + m) * NI + kt * 32 + quad * 8);
#pragma unroll
        for (int mt = 0; mt < 2; ++mt)
#pragma unroll
            for (int nt = 0; nt < 2; ++nt)
                accE[mt][nt] =
                    __builtin_amdgcn_mfma_f32_16x16x32_bf16(aE[mt], bE[nt], accE[mt][nt], 0, 0, 0);
    }
#pragma unroll
    for (int mt = 0; mt < 2; ++mt)
#pragma unroll
        for (int nt = 0; nt < 2; ++nt) {
            int d = w * 32 + nt * 16 + m;
            float bb = bemb[d];
#pragma unroll
            for (int r = 0; r < 4; ++r) {
                float v = fmaxf(accE[mt][nt][r] + bb, 0.f);
                stateL[(mt * 16 + quad * 4 + r) * 136 + d] = f2bf(v);
            }
        }
    __syncthreads();

    // ---- main GEMM: Wh = state @ W0[eh], K=128, A from LDS ----
    f32x4 acc[2][2];
#pragma unroll
    for (int mt = 0; mt < 2; ++mt)
#pragma unroll
        for (int nt = 0; nt < 2; ++nt) acc[mt][nt] = (f32x4){0.f, 0.f, 0.f, 0.f};
#pragma unroll
    for (int k0 = 0; k0 < ND; k0 += 32) {
        short8 a[2], b[2];
#pragma unroll
        for (int mt = 0; mt < 2; ++mt)
            a[mt] = *(const short8*)&stateL[(mt * 16 + m) * 136 + k0 + quad * 8];
#pragma unroll
        for (int nt = 0; nt < 2; ++nt)
            b[nt] = *(const short8*)(W0T + ((size_t)(eh * ND + w * 32 + nt * 16 + m)) * ND +
                                     k0 + quad * 8);
#pragma unroll
        for (int mt = 0; mt < 2; ++mt)
#pragma unroll
            for (int nt = 0; nt < 2; ++nt)
                acc[mt][nt] =
                    __builtin_amdgcn_mfma_f32_16x16x32_bf16(a[mt], b[nt], acc[mt][nt], 0, 0, 0);
    }

    // ---- epilogue: store WhT + fused s1/s2 ----
    int b_ = row0 >> 10, i0b = row0 & 1023;
    int ehb = eh * NB + b_;
#pragma unroll
    for (int mt = 0; mt < 2; ++mt)
#pragma unroll
        for (int nt = 0; nt < 2; ++nt) {
            int d = w * 32 + nt * 16 + m;
            int i = i0b + mt * 16 + quad * 4;
            union { unsigned short us[4]; unsigned long long u64; } pk;
#pragma unroll
            for (int r = 0; r < 4; ++r) pk.us[r] = f2bf(acc[mt][nt][r]);
            *(unsigned long long*)(WhT + (((size_t)ehb) * ND + d) * NN + i) = pk.u64;
        }
    float w1a = a1w[eh * ND + w * 32 + m], w1b = a1w[eh * ND + w * 32 + 16 + m];
    float w2a = a2w[eh * ND + w * 32 + m], w2b = a2w[eh * ND + w * 32 + 16 + m];
    float p1[2][4], p2[2][4];
#pragma unroll
    for (int mt = 0; mt < 2; ++mt)
#pragma unroll
        for (int r = 0; r < 4; ++r) {
            p1[mt][r] = acc[mt][0][r] * w1a + acc[mt][1][r] * w1b;
            p2[mt][r] = acc[mt][0][r] * w2a + acc[mt][1][r] * w2b;
        }
#pragma unroll
    for (int off = 8; off >= 1; off >>= 1)
#pragma unroll
        for (int mt = 0; mt < 2; ++mt)
#pragma unroll
            for (int r = 0; r < 4; ++r) {
                p1[mt][r] += __shfl_xor(p1[mt][r], off);
                p2[mt][r] += __shfl_xor(p2[mt][r], off);
            }
    __shared__ float sred[2][4][4][8];
    if (m == 0) {
#pragma unroll
        for (int mt = 0; mt < 2; ++mt)
#pragma unroll
            for (int r = 0; r < 4; ++r) {
                sred[0][w][quad][mt * 4 + r] = p1[mt][r];
                sred[1][w][quad][mt * 4 + r] = p2[mt][r];
            }
    }
    __syncthreads();
    if (t < 32) {
        int mt = t >> 4, quad2 = (t >> 2) & 3, r = t & 3;
        int c = mt * 4 + r;
        float v = sred[0][0][quad2][c] + sred[0][1][quad2][c] + sred[0][2][quad2][c] +
                  sred[0][3][quad2][c];
        s1[(size_t)ehb * NN + i0b + t] = (v + a1b[eh]) * LOG2E;
    } else if (t < 64) {
        int tl = t - 32;
        int mt = tl >> 4, quad2 = (tl >> 2) & 3, r = tl & 3;
        int c = mt * 4 + r;
        float v = sred[1][0][quad2][c] + sred[1][1][quad2][c] + sred[1][2][quad2][c] +
                  sred[1][3][quad2][c];
        s2[(size_t)ehb * NN + i0b + tl] = (v + a2b[eh]) * LOG2E;
    }
}

// ---------------- layer-1 filter GEMM (K=512) + s1/s2 epilogue ----------
// Also zeroes `out` (2 MB) for msg1's atomicAdd head (stream-ordered before msg1).
__global__ __launch_bounds__(256, 4) void whgemm1k(
    const unsigned short* __restrict__ state, const unsigned short* __restrict__ WT,
    unsigned short* __restrict__ WhT, const float* __restrict__ a1w,
    const float* __restrict__ a1b, const float* __restrict__ a2w,
    const float* __restrict__ a2b, float* __restrict__ s1, float* __restrict__ s2,
    float* __restrict__ outz) {
    int id = blockIdx.x;
    int g = id & 7, s_ = id >> 3;
    int eh = s_ & 3;
    int row0 = ((s_ >> 2) * 8 + g) * 32;
    int t = threadIdx.x;
    int w = t >> 6, lane = t & 63;
    int m = lane & 15, quad = lane >> 4;

    // zero out-slice for the fused head (out consumed only by msg1, later in stream)
    {
        f32x4 z = (f32x4){0.f, 0.f, 0.f, 0.f};
        for (int idx = t; idx < 128; idx += 256) ((f32x4*)outz)[(size_t)id * 128 + idx] = z;
    }

    f32x4 acc[2][2];
#pragma unroll
    for (int mt = 0; mt < 2; ++mt)
#pragma unroll
        for (int nt = 0; nt < 2; ++nt) acc[mt][nt] = (f32x4){0.f, 0.f, 0.f, 0.f};

    const unsigned short* Ab = state + (size_t)(row0 + m) * FIN1 + quad * 8;
    const unsigned short* Bb = WT + ((size_t)eh * ND + w * 32 + m) * FIN1 + quad * 8;
#pragma unroll 4
    for (int k0 = 0; k0 < FIN1; k0 += 32) {
        short8 a[2], b[2];
#pragma unroll
        for (int mt = 0; mt < 2; ++mt)
            a[mt] = *(const short8*)(Ab + (size_t)mt * 16 * FIN1 + k0);
#pragma unroll
        for (int nt = 0; nt < 2; ++nt)
            b[nt] = *(const short8*)(Bb + (size_t)nt * 16 * FIN1 + k0);
#pragma unroll
        for (int mt = 0; mt < 2; ++mt)
#pragma unroll
            for (int nt = 0; nt < 2; ++nt)
                acc[mt][nt] =
                    __builtin_amdgcn_mfma_f32_16x16x32_bf16(a[mt], b[nt], acc[mt][nt], 0, 0, 0);
    }
    int b_ = row0 >> 10, i0b = row0 & 1023;
    int ehb = eh * NB + b_;
#pragma unroll
    for (int mt = 0; mt < 2; ++mt)
#pragma unroll
        for (int nt = 0; nt < 2; ++nt) {
            int d = w * 32 + nt * 16 + m;
            int i = i0b + mt * 16 + quad * 4;
            union { unsigned short us[4]; unsigned long long u64; } pk;
#pragma unroll
            for (int r = 0; r < 4; ++r) pk.us[r] = f2bf(acc[mt][nt][r]);
            *(unsigned long long*)(WhT + (((size_t)ehb) * ND + d) * NN + i) = pk.u64;
        }
    float w1a = a1w[eh * ND + w * 32 + m], w1b = a1w[eh * ND + w * 32 + 16 + m];
    float w2a = a2w[eh * ND + w * 32 + m], w2b = a2w[eh * ND + w * 32 + 16 + m];
    float p1[2][4], p2[2][4];
#pragma unroll
    for (int mt = 0; mt < 2; ++mt)
#pragma unroll
        for (int r = 0; r < 4; ++r) {
            p1[mt][r] = acc[mt][0][r] * w1a + acc[mt][1][r] * w1b;
            p2[mt][r] = acc[mt][0][r] * w2a + acc[mt][1][r] * w2b;
        }
#pragma unroll
    for (int off = 8; off >= 1; off >>= 1)
#pragma unroll
        for (int mt = 0; mt < 2; ++mt)
#pragma unroll
            for (int r = 0; r < 4; ++r) {
                p1[mt][r] += __shfl_xor(p1[mt][r], off);
                p2[mt][r] += __shfl_xor(p2[mt][r], off);
            }
    __shared__ float sred[2][4][4][8];
    if (m == 0) {
#pragma unroll
        for (int mt = 0; mt < 2; ++mt)
#pragma unroll
            for (int r = 0; r < 4; ++r) {
                sred[0][w][quad][mt * 4 + r] = p1[mt][r];
                sred[1][w][quad][mt * 4 + r] = p2[mt][r];
            }
    }
    __syncthreads();
    if (t < 32) {
        int mt = t >> 4, quad2 = (t >> 2) & 3, r = t & 3;
        int c = mt * 4 + r;
        float v = sred[0][0][quad2][c] + sred[0][1][quad2][c] + sred[0][2][quad2][c] +
                  sred[0][3][quad2][c];
        s1[(size_t)ehb * NN + i0b + t] = (v + a1b[eh]) * LOG2E;
    } else if (t < 64) {
        int tl = t - 32;
        int mt = tl >> 4, quad2 = (tl >> 2) & 3, r = tl & 3;
        int c = mt * 4 + r;
        float v = sred[1][0][quad2][c] + sred[1][1][quad2][c] + sred[1][2][quad2][c] +
                  sred[1][3][quad2][c];
        s2[(size_t)ehb * NN + i0b + tl] = (v + a2b[eh]) * LOG2E;
    }
}

// ---------------- column sums (no-max softmax): Spart[ic][eh][b][j] ----
// edgesP: TWO f16 planes [e][b][i][j], values pre-scaled by log2e.
template <int CONV>
__global__ __launch_bounds__(256, 4) void colsumk(const float* __restrict__ edges,
                                                  unsigned short* __restrict__ edgesP,
                                                  const float* __restrict__ s1,
                                                  const float* __restrict__ s2,
                                                  float* __restrict__ Spart) {
    const size_t PO = (size_t)NB * NN * NN;   // plane stride (ushort units)
    int jt = blockIdx.x, b = blockIdx.y, ic = blockIdx.z;
    int t = threadIdx.x;
    int jp = t & 31, is = t >> 5;          // j-pair, i-chunk (16 i each)
    int j = jt * 64 + jp * 2;
    __shared__ float s1L[4][128];
    for (int idx = t; idx < 512; idx += 256) {
        int eh = idx >> 7;
        s1L[eh][idx & 127] = s1[((size_t)eh * NB + b) * NN + ic * 128 + (idx & 127)];
    }
    __syncthreads();
    float s2v[4][2], acc4[4][2];
#pragma unroll
    for (int eh = 0; eh < 4; ++eh) {
        s2v[eh][0] = s2[((size_t)eh * NB + b) * NN + j];
        s2v[eh][1] = s2[((size_t)eh * NB + b) * NN + j + 1];
        acc4[eh][0] = 0.f;
        acc4[eh][1] = 0.f;
    }
    int irow0 = ic * 128 + is * 16;
    const float4* ep = (const float4*)edges + (size_t)(b * NN + irow0) * (NN / 2) + jt * 32 + jp;
    unsigned short* pb = edgesP + (size_t)(b * NN + irow0) * NN + j;
#pragma unroll 4
    for (int ii = 0; ii < 16; ++ii) {
        unsigned q0, q1;
        if (CONV) {
            float4 ev = ep[(size_t)ii * (NN / 2)];
            q0 = (unsigned)f2h(ev.x * LOG2E) | ((unsigned)f2h(ev.z * LOG2E) << 16);
            q1 = (unsigned)f2h(ev.y * LOG2E) | ((unsigned)f2h(ev.w * LOG2E) << 16);
            *(unsigned*)(pb + (size_t)ii * NN) = q0;
            *(unsigned*)(pb + PO + (size_t)ii * NN) = q1;
        } else {
            q0 = *(const unsigned*)(pb + (size_t)ii * NN);
            q1 = *(const unsigned*)(pb + PO + (size_t)ii * NN);
        }
        float p0lo = h2f((unsigned short)(q0 & 0xffff)), p0hi = h2f((unsigned short)(q0 >> 16));
        float p1lo = h2f((unsigned short)(q1 & 0xffff)), p1hi = h2f((unsigned short)(q1 >> 16));
#pragma unroll
        for (int eh = 0; eh < 4; ++eh) {
            float sv = s1L[eh][is * 16 + ii];
            float x0 = sv + s2v[eh][0];
            x0 = fmaxf(x0, 0.2f * x0);
            acc4[eh][0] += __builtin_exp2f(x0 + (eh < 2 ? p0lo : p1lo));
            float x1 = sv + s2v[eh][1];
            x1 = fmaxf(x1, 0.2f * x1);
            acc4[eh][1] += __builtin_exp2f(x1 + (eh < 2 ? p0hi : p1hi));
        }
    }
    __shared__ float red[8][4][64];  // [is][eh][jl]
#pragma unroll
    for (int eh = 0; eh < 4; ++eh) {
        red[is][eh][jp * 2] = acc4[eh][0];
        red[is][eh][jp * 2 + 1] = acc4[eh][1];
    }
    __syncthreads();
    if (t < 256) {
        int eho = t >> 6, jlo = t & 63;
        float Sv = 0.f;
#pragma unroll
        for (int isx = 0; isx < 8; ++isx) Sv += red[isx][eho][jlo];
        Spart[(((size_t)ic * EHC + eho) * NB + b) * NN + jt * 64 + jlo] = Sv;
    }
}

// ---------------- fused msg (R2-proven structure): LDS-P, i64 tile, dbuf pstep --------
// 512 blocks x 512 thr (launch_bounds(512,4) -> 2 blocks/CU). Block = (itile16, eh, b).
// 8 waves each own d16 (MFMA A rows) and 8 i-rows of P-compute (coalesced E loads).
// edgesP f16 pre-scaled by log2e; s1/s2 pre-scaled; normalizer via stL.y = log2(S_j).
// mode0: write state1.  mode1: fused head (elu -> LDS -> mini-MFMA @ WoutT -> atomicAdd).
__global__ __launch_bounds__(512, 4) void msgk(const unsigned short* __restrict__ edgesP,
                                               const unsigned short* __restrict__ WhT,
                                               const float* __restrict__ s1,
                                               const float* __restrict__ s2,
                                               const float* __restrict__ Spart,
                                               const float* __restrict__ sb,
                                               unsigned short* __restrict__ out0,
                                               const unsigned short* __restrict__ WoutT,
                                               const float* __restrict__ bout,
                                               float* __restrict__ out, int mode) {
    int id = blockIdx.x;
    int b = id & 7;                 // XCD slot: same-b blocks share an L2
    int s_ = id >> 3;
    int eh = s_ & 3;
    int itile = s_ >> 2;            // 0..15 (64 i per block)
    int e = eh >> 1;
    int i0 = itile * 64;
    int t = threadIdx.x;
    int w = t >> 6, lane = t & 63;
    int n = lane & 15, quad = lane >> 4;
    int jl = t & 63, ib = w;        // P-compute: 8 rows x 1 col per thread

    __shared__ float2 stL[NN];                  // {s2[j], log2 S[j]} (8 KB)
    __shared__ unsigned short pA[2][64 * 72];   // P double buffer (18.4 KB)
    __shared__ unsigned short eluL[64][136];    // mode1 head staging (17.4 KB)

    int base = (eh * NB + b) * NN;
    const size_t pstr = (size_t)EHC * NB * NN;
    for (int jj = t; jj < NN; jj += 512) {
        float S = 0.f;
#pragma unroll
        for (int ic = 0; ic < 8; ++ic) S += Spart[(size_t)ic * pstr + base + jj];
        stL[jj] = make_float2(s2[base + jj], __builtin_log2f(S));
    }
    float s1r[8];
    {
        const f32x4* sp = (const f32x4*)(s1 + base + i0 + ib * 8);
        f32x4 v0 = sp[0], v1 = sp[1];
#pragma unroll
        for (int r = 0; r < 4; ++r) { s1r[r] = v0[r]; s1r[r + 4] = v1[r]; }
    }

    f32x4 acc[4];
#pragma unroll
    for (int nt = 0; nt < 4; ++nt) acc[nt] = (f32x4){0.f, 0.f, 0.f, 0.f};

    // A operand: this wave's 16 d-rows (d = w*16 + n); E: rows i0+ib*8..+8, col jl
    const unsigned short* Ab =
        WhT + ((size_t)base * ND + (size_t)(w * 16 + n) * NN) + quad * 8;
    const unsigned short* Ep = edgesP + ((size_t)(e * NB + b) * NN + i0 + ib * 8) * NN + jl;
    __syncthreads();  // stL ready

    unsigned short evA[8], evB[8];
    short8 aA[2], aB[2];

    auto loadE = [&](unsigned short* ev, int j0) {
#pragma unroll
        for (int q = 0; q < 8; ++q) ev[q] = Ep[(size_t)q * NN + j0];
    };
    auto loadA = [&](short8* av, int j0) {
#pragma unroll
        for (int kt = 0; kt < 2; ++kt)
            av[kt] = *(const short8*)(Ab + kt * 32 + j0);
    };
    auto pstep = [&](const unsigned short* ev, const short8* av, int j0, int buf) {
        float2 stj = stL[j0 + jl];
#pragma unroll
        for (int q = 0; q < 8; ++q) {
            float x = s1r[q] + stj.x;
            x = fmaxf(x, 0.2f * x);
            x += h2f(ev[q]) - stj.y;
            pA[buf][(ib * 8 + q) * 72 + jl] = f2bf(__builtin_exp2f(x));
        }
        __syncthreads();
#pragma unroll
        for (int kt = 0; kt < 2; ++kt) {
            short8 bv[4];
#pragma unroll
            for (int nt = 0; nt < 4; ++nt)
                bv[nt] = *(const short8*)&pA[buf][(nt * 16 + n) * 72 + kt * 32 + quad * 8];
#pragma unroll
            for (int nt = 0; nt < 4; ++nt)
                acc[nt] =
                    __builtin_amdgcn_mfma_f32_16x16x32_bf16(av[kt], bv[nt], acc[nt], 0, 0, 0);
        }
    };

    loadE(evA, 0);
    loadA(aA, 0);
    for (int sp2 = 0; sp2 < 8; ++sp2) {
        int j0 = sp2 * 128;
        loadE(evB, j0 + 64);
        loadA(aB, j0 + 64);
        pstep(evA, aA, j0, 0);
        if (sp2 < 7) {
            loadE(evA, j0 + 128);
            loadA(aA, j0 + 128);
        }
        pstep(evB, aB, j0 + 64, 1);
    }

    // epilogue: C row(quad*4+r) = d-local, col(lane&15) = i-local
    int d0 = w * 16 + quad * 4;
    f32x4 sbv = *(const f32x4*)&sb[eh * ND + d0];
    if (mode == 0) {
#pragma unroll
        for (int nt = 0; nt < 4; ++nt) {
            int i = i0 + nt * 16 + n;
            union { unsigned short us[4]; unsigned long long u64; } pk;
#pragma unroll
            for (int r = 0; r < 4; ++r) pk.us[r] = f2bf(acc[nt][r] + sbv[r]);
            *(unsigned long long*)(out0 + (size_t)(b * NN + i) * FIN1 + eh * ND + d0) = pk.u64;
        }
    } else {
        // fused head: out[i][o] += 0.25*(elu(C+sb) @ Wout + bout)
#pragma unroll
        for (int nt = 0; nt < 4; ++nt) {
            union { unsigned short us[4]; unsigned long long u64; } pk;
#pragma unroll
            for (int r = 0; r < 4; ++r) {
                float v = acc[nt][r] + sbv[r];
                pk.us[r] = f2bf(v > 0.f ? v : expm1f(v));
            }
            *(unsigned long long*)&eluL[nt * 16 + n][d0] = pk.u64;
        }
        __syncthreads();
        // head mini-GEMM: 8 waves cover (it 0..3) x (ot 0..3), 2 tiles each
        int it = w & 3, ot0 = w >> 2;
#pragma unroll
        for (int oo = 0; oo < 2; ++oo) {
            int ot = ot0 + oo * 2;
            int o = ot * 16 + n;
            f32x4 hacc = (f32x4){0.f, 0.f, 0.f, 0.f};
#pragma unroll
            for (int k0 = 0; k0 < 4; ++k0) {
                short8 av = *(const short8*)&eluL[it * 16 + n][k0 * 32 + quad * 8];
                short8 bv = *(const short8*)(WoutT + (size_t)o * ND + k0 * 32 + quad * 8);
                hacc = __builtin_amdgcn_mfma_f32_16x16x32_bf16(av, bv, hacc, 0, 0, 0);
            }
            float bo = bout[o];
            float* op = out + (size_t)(b * NN + i0 + it * 16 + quad * 4) * NO + o;
#pragma unroll
            for (int r = 0; r < 4; ++r)
                atomicAdd(op + (size_t)r * NO, 0.25f * hacc[r] + 0.25f * bo);
        }
    }
}

extern "C" void kernel_launch(void* const* d_in, const int* in_sizes, int n_in,
                              void* d_out, int out_size, void* d_ws, size_t ws_size,
                              hipStream_t stream) {
    const float* nodes = (const float*)d_in[0];
    const float* edges = (const float*)d_in[1];
    const float* Wemb = (const float*)d_in[2];
    const float* bemb = (const float*)d_in[3];
    const float* W0 = (const float*)d_in[4];
    const float* A1w0 = (const float*)d_in[5];
    const float* A1b0 = (const float*)d_in[6];
    const float* A2w0 = (const float*)d_in[7];
    const float* A2b0 = (const float*)d_in[8];
    const float* SB0 = (const float*)d_in[9];
    const float* W1 = (const float*)d_in[10];
    const float* A1w1 = (const float*)d_in[11];
    const float* A1b1 = (const float*)d_in[12];
    const float* A2w1 = (const float*)d_in[13];
    const float* A2b1 = (const float*)d_in[14];
    const float* SB1 = (const float*)d_in[15];
    const float* Wout = (const float*)d_in[16];
    const float* bout = (const float*)d_in[17];
    float* out = (float*)d_out;

    char* p = (char*)d_ws;
    auto alloc = [&](size_t bytes) {
        char* r = p;
        p += (bytes + 255) & ~(size_t)255;
        return r;
    };
    unsigned short* W0T = (unsigned short*)alloc((size_t)EHC * ND * ND * 2);
    unsigned short* W1T = (unsigned short*)alloc((size_t)EHC * ND * FIN1 * 2);
    unsigned short* WembT = (unsigned short*)alloc((size_t)ND * NI * 2);
    unsigned short* WoutT = (unsigned short*)alloc((size_t)ND * NO * 2);
    unsigned short* WhT = (unsigned short*)alloc((size_t)EHC * BN * ND * 2);
    unsigned short* state1 = (unsigned short*)alloc((size_t)BN * FIN1 * 2);
    float* s1b = (float*)alloc((size_t)EHC * BN * 4);
    float* s2b = (float*)alloc((size_t)EHC * BN * 4);
    float* Spart = (float*)alloc((size_t)8 * EHC * BN * 4);
    unsigned short* edgesP = (unsigned short*)alloc((size_t)2 * NB * NN * NN * 2);

    prepTk<<<1344, 256, 0, stream>>>(W0, W1, Wemb, Wout, W0T, W1T, WembT, WoutT);
    // layer 0 (embed fused into filter GEMM)
    embwh0k<<<1024, 256, 0, stream>>>(nodes, WembT, bemb, W0T, WhT, A1w0, A1b0, A2w0, A2b0,
                                      s1b, s2b);
    colsumk<1><<<dim3(NN / 64, NB, 8), 256, 0, stream>>>(edges, edgesP, s1b, s2b, Spart);
    msgk<<<512, 512, 0, stream>>>(edgesP, WhT, s1b, s2b, Spart, SB0, state1, WoutT, bout,
                                  out, 0);
    // layer 1 (whgemm1k also zeroes `out` for the fused head)
    whgemm1k<<<1024, 256, 0, stream>>>(state1, W1T, WhT, A1w1, A1b1, A2w1, A2b1, s1b, s2b,
                                       out);
    colsumk<0><<<dim3(NN / 64, NB, 8), 256, 0, stream>>>(edges, edgesP, s1b, s2b, Spart);
    msgk<<<512, 512, 0, stream>>>(edgesP, WhT, s1b, s2b, Spart, SB1, state1, WoutT, bout,
                                  out, 1);
}